// Round 6
// baseline (1080.388 us; speedup 1.0000x reference)
//
#include <hip/hip_runtime.h>
#include <math.h>

#define BB 8
#define CC 256
#define NTOK 2304   // 48*48
#define NT 144      // 16-token k-tiles
#define LOG2E 1.4426950408889634f
#define BIAS2 72.134752f   // ~50*log2(e): p = 2^(s-BIAS2), overflow-free, no-max softmax

typedef __attribute__((ext_vector_type(4))) float f32x4;
typedef __attribute__((ext_vector_type(8))) short s16x8;
typedef __attribute__((ext_vector_type(4))) short s16x4;

__device__ inline unsigned short f2bf(float x) {
  unsigned u = __builtin_bit_cast(unsigned, x);
  return (unsigned short)((u + 0x7FFFu + ((u >> 16) & 1u)) >> 16);
}
__device__ inline float bf2f(unsigned short h) {
  return __builtin_bit_cast(float, (unsigned)h << 16);
}

// async global -> LDS, 16B per lane, zero VGPR round-trip
__device__ inline void async16(void* lds, const void* g) {
  __builtin_amdgcn_global_load_lds(
      (const __attribute__((address_space(1))) unsigned int*)g,
      (__attribute__((address_space(3))) unsigned int*)lds, 16, 0, 0);
}

// ---------------- projection ----------------
// Per batch: Y[n][d] = sum_c X[c][n] * W[d][c]   (fp32 accumulate)
// MODE 0: write Qh,Ql bf16 [n][d], scaled by LOG2E (split hi/lo)
// MODE 1: write Kh bf16 [n][d]
// MODE 2: write V^T bf16 [d][n]
template<int MODE>
__global__ __launch_bounds__(256)
void proj_kernel(const float* __restrict__ X, const float* __restrict__ W,
                 unsigned short* __restrict__ Y0, unsigned short* __restrict__ Y1) {
  const int n0 = blockIdx.x * 64;
  const int d0 = blockIdx.y * 64;
  const int b  = blockIdx.z;
  const float* Xb = X + (size_t)b * CC * NTOK;
  unsigned short* Yb0 = Y0 + (size_t)b * CC * NTOK;
  unsigned short* Yb1 = (MODE == 0) ? (Y1 + (size_t)b * CC * NTOK) : nullptr;

  __shared__ float Wt[32][68];   // Wt[c][d]
  __shared__ float Xs[32][68];   // Xs[c][n]

  const int t  = threadIdx.x;
  const int tn = t & 15;
  const int td = t >> 4;

  float acc[4][4];
  #pragma unroll
  for (int i = 0; i < 4; i++)
    #pragma unroll
    for (int j = 0; j < 4; j++) acc[i][j] = 0.f;

  for (int c0 = 0; c0 < CC; c0 += 32) {
    {
      const int c = t & 31, dr = t >> 5;
      #pragma unroll
      for (int j = 0; j < 8; j++) {
        int d = dr + 8 * j;
        Wt[c][d] = W[(size_t)(d0 + d) * CC + c0 + c];
      }
    }
    {
      const int n = t & 63, cr = t >> 6;
      #pragma unroll
      for (int j = 0; j < 8; j++) {
        int c = cr + 4 * j;
        Xs[c][n] = Xb[(size_t)(c0 + c) * NTOK + n0 + n];
      }
    }
    __syncthreads();
    #pragma unroll
    for (int c = 0; c < 32; c++) {
      float4 wv = *(const float4*)&Wt[c][td * 4];
      float4 xv = *(const float4*)&Xs[c][tn * 4];
      float wf[4] = {wv.x, wv.y, wv.z, wv.w};
      float xf[4] = {xv.x, xv.y, xv.z, xv.w};
      #pragma unroll
      for (int i = 0; i < 4; i++)
        #pragma unroll
        for (int j = 0; j < 4; j++)
          acc[i][j] = fmaf(xf[i], wf[j], acc[i][j]);
    }
    __syncthreads();
  }

  if (MODE == 0) {
    #pragma unroll
    for (int i = 0; i < 4; i++) {
      s16x4 hv, lv;
      #pragma unroll
      for (int j = 0; j < 4; j++) {
        float v = acc[i][j] * LOG2E;
        unsigned short h = f2bf(v);
        hv[j] = (short)h;
        lv[j] = (short)f2bf(v - bf2f(h));
      }
      int n = n0 + tn * 4 + i, d = d0 + td * 4;
      *(s16x4*)&Yb0[(size_t)n * CC + d] = hv;
      *(s16x4*)&Yb1[(size_t)n * CC + d] = lv;
    }
  } else if (MODE == 1) {
    #pragma unroll
    for (int i = 0; i < 4; i++) {
      s16x4 hv;
      #pragma unroll
      for (int j = 0; j < 4; j++) hv[j] = (short)f2bf(acc[i][j]);
      int n = n0 + tn * 4 + i, d = d0 + td * 4;
      *(s16x4*)&Yb0[(size_t)n * CC + d] = hv;
    }
  } else {
    #pragma unroll
    for (int j = 0; j < 4; j++) {
      s16x4 v;
      #pragma unroll
      for (int i = 0; i < 4; i++) v[i] = (short)f2bf(acc[i][j]);
      int d = d0 + td * 4 + j, n = n0 + tn * 4;
      *(s16x4*)&Yb0[(size_t)d * NTOK + n] = v;
    }
  }
}

// ---------------- fused dual-softmax MFMA attention, prefetch-pipelined ----------------
// 4 waves/block, 64 q-rows (16/wave). 16-tok k-tiles (144). K1+K2 double-buffered
// (staged 1 tile ahead), V quad-buffered (staged 2 ahead; PV reads V one phase late).
// global_load_lds staging issued at phase START, drained by the barrier at phase END
// -> L2 latency hidden under compute. LDS 70.7KB -> 2 blocks/CU.
__global__ __launch_bounds__(256, 2)
void attn_kernel(const unsigned short* __restrict__ Qh, const unsigned short* __restrict__ Ql,
                 const unsigned short* __restrict__ K1, const unsigned short* __restrict__ K2,
                 const unsigned short* __restrict__ Vt, const float* __restrict__ qry,
                 const float* __restrict__ mup, float* __restrict__ out) {
  // [0,32K): kbuf[2] (each K1 8K | K2 8K) ; [32K,64K): vbuf[4] (8K each) ;
  // [64K... wait PsW at 65536: float[4][16][20] = 5120 -> total 70656
  __shared__ alignas(16) char smem[70656];
  char* const kbp0 = smem;
  char* const kbp1 = smem + 16384;
  char* const vbp0 = smem + 32768;
  char* const vbp1 = smem + 40960;
  char* const vbp2 = smem + 49152;
  char* const vbp3 = smem + 57344;
  float (*PsW)[20] = (float (*)[20])(smem + 65536 + (threadIdx.x >> 6) * 1280);

  const int t = threadIdx.x;
  const int w = t >> 6, l = t & 63, g = l >> 4, c = l & 15;
  const int bid = blockIdx.x;
  const int b = bid & 7, qt = bid >> 3;     // batch -> XCD pin; q-tile 0..35
  const int q0 = qt * 64 + w * 16;          // this wave's 16 q-rows
  const size_t bo = (size_t)b * CC * NTOK;

  const char* Qhb = (const char*)(Qh + bo);
  const char* Qlb = (const char*)(Ql + bo);
  const char* K1b = (const char*)(K1 + bo);
  const char* K2b = (const char*)(K2 + bo);
  const char* Vtb = (const char*)(Vt + bo);

  // ---- staging lane offsets: per tile, wave w owns chunks {w, w+4} of each region.
  // K region/tile: 16 tok x 512B, pre-swizzled source col ^ ((tok&7)<<4).
  // V region/tile: 256 d-rows x 32B, linear.
  int koff[2], voff[2], kdst[2];
  #pragma unroll
  for (int i = 0; i < 2; i++) {
    int ck = w + 4 * i;
    int tokl = ck * 2 + (l >> 5);
    koff[i] = tokl * 512 + (((l & 31) * 16) ^ ((tokl & 7) << 4));
    kdst[i] = ck * 1024;
    voff[i] = (ck * 32 + (l >> 1)) * 4608 + (l & 1) * 16;
  }

  // read-side swizzle constants
  int kxor[8];
  #pragma unroll
  for (int dc = 0; dc < 8; dc++)
    kxor[dc] = (dc * 64 + g * 16) ^ ((c & 7) << 4);

  // Q fragments resident (A-operand: lane(g,c) holds row q0+c, k-slice dc*32+g*8+0..7)
  s16x8 qh[8], ql[8];
  #pragma unroll
  for (int dc = 0; dc < 8; dc++) {
    int off = (q0 + c) * 512 + dc * 64 + g * 16;
    qh[dc] = *(const s16x8*)(Qhb + off);
    ql[dc] = *(const s16x8*)(Qlb + off);
  }

  f32x4 a1[16], a2[16];
  #pragma unroll
  for (int dt = 0; dt < 16; dt++) {
    a1[dt] = (f32x4){0.f, 0.f, 0.f, 0.f};
    a2[dt] = (f32x4){0.f, 0.f, 0.f, 0.f};
  }
  float lr1[4] = {0.f, 0.f, 0.f, 0.f};
  float lr2[4] = {0.f, 0.f, 0.f, 0.f};
  s16x8 paE[2], paO[2];

  auto STAGE_K = [&](char* kb, int tile) {
    const char* s1 = K1b + (size_t)tile * 8192;
    const char* s2 = K2b + (size_t)tile * 8192;
    async16(kb + kdst[0], s1 + koff[0]);
    async16(kb + kdst[1], s1 + koff[1]);
    async16(kb + 8192 + kdst[0], s2 + koff[0]);
    async16(kb + 8192 + kdst[1], s2 + koff[1]);
  };
  auto STAGE_V = [&](char* vb, int tile) {
    const char* sv = Vtb + (size_t)tile * 32;
    async16(vb + kdst[0], sv + voff[0]);
    async16(vb + kdst[1], sv + voff[1]);
  };

  // S phase on one 16-tok tile; parity selects which pa half-set this fills
  auto SPH = [&](const char* kb, int parity) {
    #pragma unroll
    for (int p = 0; p < 2; p++) {
      const char* Kp = kb + p * 8192;
      f32x4 s = (f32x4){0.f, 0.f, 0.f, 0.f};
      const char* Kt = Kp + c * 512;
      #pragma unroll
      for (int dc = 0; dc < 8; dc++) {
        s16x8 kf = *(const s16x8*)(Kt + kxor[dc]);
        s = __builtin_amdgcn_mfma_f32_16x16x32_bf16(qh[dc], kf, s, 0, 0, 0);
        s = __builtin_amdgcn_mfma_f32_16x16x32_bf16(ql[dc], kf, s, 0, 0, 0);
      }
      float* lr = p ? lr2 : lr1;
      #pragma unroll
      for (int j = 0; j < 4; j++) {
        float pv = exp2f(s[j] - BIAS2);
        lr[j] += pv;
        PsW[g * 4 + j][c] = pv;   // P[q-row][tok]
      }
      // wave-local transpose read (lanes pick their k-slice; lgkmcnt by compiler)
      const float* Pr = &PsW[c][(g & 1) * 8];
      f32x4 lo = *(const f32x4*)Pr;
      f32x4 hi = *(const f32x4*)(Pr + 4);
      s16x8 v;
      #pragma unroll
      for (int j = 0; j < 4; j++) {
        v[j]     = (short)f2bf(lo[j]);
        v[4 + j] = (short)f2bf(hi[j]);
      }
      if (parity == 0) paE[p] = v;
      else             paO[p] = v;
    }
  };

  // PV over a tile pair: lanes g<2 take V from bufA (toks 0..15), g>=2 from bufB
  auto PV = [&](const char* vbA, const char* vbB) {
    s16x8 pa0 = (g < 2) ? paE[0] : paO[0];
    s16x8 pa1 = (g < 2) ? paE[1] : paO[1];
    const char* vb = ((g < 2) ? vbA : vbB) + c * 32 + (g & 1) * 16;
    #pragma unroll
    for (int dt = 0; dt < 16; dt++) {
      s16x8 vf = *(const s16x8*)(vb + dt * 512);
      a1[dt] = __builtin_amdgcn_mfma_f32_16x16x32_bf16(pa0, vf, a1[dt], 0, 0, 0);
      a2[dt] = __builtin_amdgcn_mfma_f32_16x16x32_bf16(pa1, vf, a2[dt], 0, 0, 0);
    }
  };

  // ---- prologue: K(0)->kb0, V(0)->vb0, V(1)->vb1
  STAGE_K(kbp0, 0);
  STAGE_V(vbp0, 0);
  STAGE_V(vbp1, 1);
  __syncthreads();

  char* const kbl[2] = {kbp0, kbp1};
  char* const vbl[4] = {vbp0, vbp1, vbp2, vbp3};

  for (int t4 = 0; t4 < NT; t4 += 4) {
    #pragma unroll
    for (int u = 0; u < 4; u++) {
      const int tt = t4 + u;
      if (tt + 1 < NT) STAGE_K(kbl[(u + 1) & 1], tt + 1);   // K one ahead
      if (tt + 2 < NT) STAGE_V(vbl[(u + 2) & 3], tt + 2);   // V two ahead
      SPH(kbl[u & 1], u & 1);
      if (u & 1) PV(vbl[(u + 3) & 3], vbl[u & 3]);
      __syncthreads();   // drains this phase's staging (issued ~600cy earlier)
    }
  }

  // ---- row-sum reduce across the 16 c-lanes of each g group
  #pragma unroll
  for (int j = 0; j < 4; j++) {
    #pragma unroll
    for (int off = 1; off < 16; off <<= 1) {
      lr1[j] += __shfl_xor(lr1[j], off);
      lr2[j] += __shfl_xor(lr2[j], off);
    }
  }
  const float mu = mup[0];
  const float cw1 = 0.5f / (0.5f + mu);
  const float cw2 = mu / (0.5f + mu);
  float r1[4], r2[4];
  #pragma unroll
  for (int j = 0; j < 4; j++) { r1[j] = cw1 / lr1[j]; r2[j] = cw2 / lr2[j]; }

  // ---- per-wave transposed epilogue (wave-private [16][68] f32 in kbuf area)
  float* Ws = (float*)(smem + w * 4352);
  const int q = l & 15, ds = l >> 4;
  #pragma unroll
  for (int ch = 0; ch < 4; ch++) {
    #pragma unroll
    for (int dtp = 0; dtp < 4; dtp++) {
      const int dt = ch * 4 + dtp;
      #pragma unroll
      for (int j = 0; j < 4; j++)
        Ws[(g * 4 + j) * 68 + dtp * 16 + c] = a1[dt][j] * r1[j] + a2[dt][j] * r2[j];
    }
    // wave-local write->read; compiler inserts lgkmcnt waits
    #pragma unroll
    for (int i = 0; i < 16; i++) {
      int d = ch * 64 + i * 4 + ds;
      size_t gi = bo + (size_t)d * NTOK + q0 + q;
      out[gi] = qry[gi] + Ws[q * 68 + i * 4 + ds];
    }
  }
}

extern "C" void kernel_launch(void* const* d_in, const int* in_sizes, int n_in,
                              void* d_out, int out_size, void* d_ws, size_t ws_size,
                              hipStream_t stream) {
  const float* qry  = (const float*)d_in[0];
  const float* mask = (const float*)d_in[1];
  const float* fts  = (const float*)d_in[2];
  const float* Wq   = (const float*)d_in[3];
  const float* Wk   = (const float*)d_in[4];
  const float* Wv   = (const float*)d_in[5];
  const float* mu   = (const float*)d_in[6];
  float* out = (float*)d_out;

  const size_t SZ = (size_t)BB * CC * NTOK;
  unsigned short* Qhw = (unsigned short*)d_ws;
  unsigned short* Qlw = Qhw + SZ;
  unsigned short* K1w = Qhw + 2 * SZ;
  unsigned short* K2w = Qhw + 3 * SZ;
  unsigned short* Vtw = Qhw + 4 * SZ;

  dim3 pg(NTOK / 64, CC / 64, BB);
  proj_kernel<0><<<pg, 256, 0, stream>>>(qry,  Wq, Qhw, Qlw);
  proj_kernel<1><<<pg, 256, 0, stream>>>(fts,  Wk, K1w, nullptr);
  proj_kernel<1><<<pg, 256, 0, stream>>>(mask, Wk, K2w, nullptr);
  proj_kernel<2><<<pg, 256, 0, stream>>>(fts,  Wv, Vtw, nullptr);

  attn_kernel<<<BB * (NTOK / 64), 256, 0, stream>>>(Qhw, Qlw, K1w, K2w, Vtw, qry, mu, out);
}

// Round 7
// 366.766 us; speedup vs baseline: 2.9457x; 2.9457x over previous
//
#include <hip/hip_runtime.h>
#include <math.h>

#define BB 8
#define CC 256
#define NTOK 2304   // 48*48
#define NT 144      // 16-token k-tiles
#define NP 72       // 32-token pairs
#define LOG2E 1.4426950408889634f
#define BIAS2 72.134752f   // p = 2^(s-BIAS2): overflow-free no-max softmax (fp32/bf16 range)

typedef __attribute__((ext_vector_type(4))) float f32x4;
typedef __attribute__((ext_vector_type(8))) short s16x8;
typedef __attribute__((ext_vector_type(4))) short s16x4;

__device__ inline unsigned short f2bf(float x) {
  unsigned u = __builtin_bit_cast(unsigned, x);
  return (unsigned short)((u + 0x7FFFu + ((u >> 16) & 1u)) >> 16);
}
__device__ inline unsigned short f2h(float x) {
  _Float16 h = (_Float16)x;
  return __builtin_bit_cast(unsigned short, h);
}

// async global -> LDS, 16B/lane; LDS dst = wave-uniform base + lane*16
__device__ inline void async16(void* lds, const void* g) {
  __builtin_amdgcn_global_load_lds(
      (const __attribute__((address_space(1))) unsigned int*)g,
      (__attribute__((address_space(3))) unsigned int*)lds, 16, 0, 0);
}

// ---------------- projection ----------------
// Per batch: Y[n][d] = sum_c X[c][n] * W[d][c]   (fp32 accumulate)
// MODE 0: fp16 [n][d], scaled by LOG2E (Q)
// MODE 1: fp16 [n][d]                  (K1/K2)
// MODE 2: bf16 V^T [d][n]              (V)
template<int MODE>
__global__ __launch_bounds__(256)
void proj_kernel(const float* __restrict__ X, const float* __restrict__ W,
                 unsigned short* __restrict__ Y0) {
  const int n0 = blockIdx.x * 64;
  const int d0 = blockIdx.y * 64;
  const int b  = blockIdx.z;
  const float* Xb = X + (size_t)b * CC * NTOK;
  unsigned short* Yb0 = Y0 + (size_t)b * CC * NTOK;

  __shared__ float Wt[32][68];   // Wt[c][d]
  __shared__ float Xs[32][68];   // Xs[c][n]

  const int t  = threadIdx.x;
  const int tn = t & 15;
  const int td = t >> 4;

  float acc[4][4];
  #pragma unroll
  for (int i = 0; i < 4; i++)
    #pragma unroll
    for (int j = 0; j < 4; j++) acc[i][j] = 0.f;

  for (int c0 = 0; c0 < CC; c0 += 32) {
    {
      const int c = t & 31, dr = t >> 5;
      #pragma unroll
      for (int j = 0; j < 8; j++) {
        int d = dr + 8 * j;
        Wt[c][d] = W[(size_t)(d0 + d) * CC + c0 + c];
      }
    }
    {
      const int n = t & 63, cr = t >> 6;
      #pragma unroll
      for (int j = 0; j < 8; j++) {
        int c = cr + 4 * j;
        Xs[c][n] = Xb[(size_t)(c0 + c) * NTOK + n0 + n];
      }
    }
    __syncthreads();
    #pragma unroll
    for (int c = 0; c < 32; c++) {
      float4 wv = *(const float4*)&Wt[c][td * 4];
      float4 xv = *(const float4*)&Xs[c][tn * 4];
      float wf[4] = {wv.x, wv.y, wv.z, wv.w};
      float xf[4] = {xv.x, xv.y, xv.z, xv.w};
      #pragma unroll
      for (int i = 0; i < 4; i++)
        #pragma unroll
        for (int j = 0; j < 4; j++)
          acc[i][j] = fmaf(xf[i], wf[j], acc[i][j]);
    }
    __syncthreads();
  }

  if (MODE == 0 || MODE == 1) {
    #pragma unroll
    for (int i = 0; i < 4; i++) {
      s16x4 hv;
      #pragma unroll
      for (int j = 0; j < 4; j++) {
        float v = (MODE == 0) ? acc[i][j] * LOG2E : acc[i][j];
        hv[j] = (short)f2h(v);
      }
      int n = n0 + tn * 4 + i, d = d0 + td * 4;
      *(s16x4*)&Yb0[(size_t)n * CC + d] = hv;
    }
  } else {
    #pragma unroll
    for (int j = 0; j < 4; j++) {
      s16x4 v;
      #pragma unroll
      for (int i = 0; i < 4; i++) v[i] = (short)f2bf(acc[i][j]);
      int d = d0 + td * 4 + j, n = n0 + tn * 4;
      *(s16x4*)&Yb0[(size_t)d * NTOK + n] = v;
    }
  }
}

// ---------------- fused dual-softmax MFMA attention ----------------
// 4 waves, 64 q-rows (16/wave). 16-tok tiles, K double-buffered, V pair-buffered.
// Per phase: STAGE(next) -> compute(cur) -> ONE barrier (drain covers a full phase).
// S in fp16 (Q,K fp16: 1 MFMA per frag), PV in bf16 with paired K=32 A-fragments.
__global__ __launch_bounds__(256, 2)
void attn_kernel(const unsigned short* __restrict__ Qf, const unsigned short* __restrict__ K1,
                 const unsigned short* __restrict__ K2, const unsigned short* __restrict__ Vt,
                 const float* __restrict__ qry, const float* __restrict__ mup,
                 float* __restrict__ out) {
  // kb0 @0 (16K: K1|K2), kb1 @16384, vb0 @32768 (16K: halfA|halfB), vb1 @49152,
  // P @65536: per wave 3 x [16][18] f32 (Pe0, Pe1, Podd) = 3456 B
  __shared__ alignas(16) char smem[79360];
  char* const kb0 = smem;
  char* const kb1 = smem + 16384;

  const int t = threadIdx.x;
  const int w = t >> 6, l = t & 63, g = l >> 4, c = l & 15;
  const int bid = blockIdx.x;
  const int b = bid & 7, qt = bid >> 3;     // batch -> XCD pin
  const int q0 = qt * 64 + w * 16;
  const size_t bo = (size_t)b * CC * NTOK;

  const char* Qb  = (const char*)(Qf + bo);
  const char* K1b = (const char*)(K1 + bo);
  const char* K2b = (const char*)(K2 + bo);
  const char* Vtb = (const char*)(Vt + bo);

  float* const Pe0 = (float*)(smem + 65536 + w * 3456);
  float* const Pe1 = Pe0 + 288;            // 1152 B
  float* const Pod = Pe0 + 576;

  // staging lane offsets: wave w owns chunks {w, w+4} per 8KB region
  int koff[2], voff[2], cdst[2];
  #pragma unroll
  for (int j = 0; j < 2; j++) {
    int ck = w + 4 * j;
    int tok = ck * 2 + (l >> 5);
    koff[j] = tok * 512 + (((l & 31) * 16) ^ ((tok & 7) << 4));  // pre-swizzled src
    voff[j] = (ck * 32 + (l >> 1)) * 4608 + (l & 1) * 16;
    cdst[j] = ck * 1024 + l * 16;
  }

  int kxor[8];
  #pragma unroll
  for (int dc = 0; dc < 8; dc++)
    kxor[dc] = (dc * 64 + g * 16) ^ ((c & 7) << 4);

  // Q fp16 fragments resident: lane(g,c) = row q0+c, k-slice dc*32+g*8..+7
  s16x8 qf[8];
  #pragma unroll
  for (int dc = 0; dc < 8; dc++)
    qf[dc] = *(const s16x8*)(Qb + (q0 + c) * 512 + dc * 64 + g * 16);

  f32x4 a1[16], a2[16];
  #pragma unroll
  for (int dt = 0; dt < 16; dt++) {
    a1[dt] = (f32x4){0.f, 0.f, 0.f, 0.f};
    a2[dt] = (f32x4){0.f, 0.f, 0.f, 0.f};
  }
  float lr1[4] = {0.f, 0.f, 0.f, 0.f};
  float lr2[4] = {0.f, 0.f, 0.f, 0.f};

#define STAGE_K(KB, TILE)                                                  \
  do {                                                                     \
    _Pragma("unroll")                                                      \
    for (int pp_ = 0; pp_ < 2; pp_++) {                                    \
      const char* ks_ = (pp_ ? K2b : K1b) + (size_t)(TILE) * 8192;         \
      async16((KB) + pp_ * 8192 + cdst[0], ks_ + koff[0]);                 \
      async16((KB) + pp_ * 8192 + cdst[1], ks_ + koff[1]);                 \
    }                                                                      \
  } while (0)

#define STAGE_V(VB, PAIR)                                                  \
  do {                                                                     \
    _Pragma("unroll")                                                      \
    for (int h_ = 0; h_ < 2; h_++) {                                       \
      const char* vs_ = Vtb + (PAIR) * 64 + h_ * 32;                       \
      async16((VB) + h_ * 8192 + cdst[0], vs_ + voff[0]);                  \
      async16((VB) + h_ * 8192 + cdst[1], vs_ + voff[1]);                  \
    }                                                                      \
  } while (0)

  // prologue
  STAGE_K(kb0, 0);
  STAGE_V(smem + 32768, 0);
  __syncthreads();

  for (int p = 0; p < NP; p++) {
    char* vcur = smem + 32768 + (p & 1) * 16384;
    char* vnxt = smem + 32768 + ((p & 1) ^ 1) * 16384;

    // ======== even phase: tile 2p from kb0 ========
    STAGE_K(kb1, 2 * p + 1);              // always valid (<=143)
    #pragma unroll
    for (int pp = 0; pp < 2; pp++) {
      const char* Kt = kb0 + pp * 8192 + c * 512;
      f32x4 s = (f32x4){0.f, 0.f, 0.f, 0.f};
      #pragma unroll
      for (int dc = 0; dc < 8; dc++) {
        s16x8 kf = *(const s16x8*)(Kt + kxor[dc]);
        s = __builtin_amdgcn_mfma_f32_16x16x32_f16(qf[dc], kf, s, 0, 0, 0);
      }
      float* lr = pp ? lr2 : lr1;
      float* Pe = pp ? Pe1 : Pe0;
      #pragma unroll
      for (int j = 0; j < 4; j++) {
        float pv = exp2f(s[j] - BIAS2);
        lr[j] += pv;
        Pe[(g * 4 + j) * 18 + c] = pv;
      }
    }
    __syncthreads();

    // ======== odd phase: tile 2p+1 from kb1, PV on vcur ========
    if (p + 1 < NP) {
      STAGE_K(kb0, 2 * p + 2);
      STAGE_V(vnxt, p + 1);
    }
    s16x8 pa0, pa1;
    #pragma unroll
    for (int pp = 0; pp < 2; pp++) {
      const char* Kt = kb1 + pp * 8192 + c * 512;
      f32x4 s = (f32x4){0.f, 0.f, 0.f, 0.f};
      #pragma unroll
      for (int dc = 0; dc < 8; dc++) {
        s16x8 kf = *(const s16x8*)(Kt + kxor[dc]);
        s = __builtin_amdgcn_mfma_f32_16x16x32_f16(qf[dc], kf, s, 0, 0, 0);
      }
      float* lr = pp ? lr2 : lr1;
      #pragma unroll
      for (int j = 0; j < 4; j++) {
        float pv = exp2f(s[j] - BIAS2);
        lr[j] += pv;
        Pod[(g * 4 + j) * 18 + c] = pv;
      }
      // assemble paired A-frag: g<2 lanes take even tile (Pe), g>=2 odd tile (Pod)
      const float* src = ((g < 2) ? (pp ? Pe1 : Pe0) : Pod) + c * 18 + (g & 1) * 8;
      s16x8 v;
      #pragma unroll
      for (int i = 0; i < 8; i++) v[i] = (short)f2bf(src[i]);
      if (pp == 0) pa0 = v; else pa1 = v;
    }
    {
      const char* vbase = vcur + ((g >= 2) ? 8192 : 0) + c * 32 + (g & 1) * 16;
      #pragma unroll
      for (int dt = 0; dt < 16; dt++) {
        s16x8 vf = *(const s16x8*)(vbase + dt * 512);
        a1[dt] = __builtin_amdgcn_mfma_f32_16x16x32_bf16(pa0, vf, a1[dt], 0, 0, 0);
        a2[dt] = __builtin_amdgcn_mfma_f32_16x16x32_bf16(pa1, vf, a2[dt], 0, 0, 0);
      }
    }
    __syncthreads();
  }
#undef STAGE_K
#undef STAGE_V

  // ---- row-sum reduce across the 16 c-lanes of each g group
  #pragma unroll
  for (int j = 0; j < 4; j++) {
    #pragma unroll
    for (int off = 1; off < 16; off <<= 1) {
      lr1[j] += __shfl_xor(lr1[j], off);
      lr2[j] += __shfl_xor(lr2[j], off);
    }
  }
  const float mu = mup[0];
  const float cw1 = 0.5f / (0.5f + mu);
  const float cw2 = mu / (0.5f + mu);
  float r1[4], r2[4];
  #pragma unroll
  for (int j = 0; j < 4; j++) { r1[j] = cw1 / lr1[j]; r2[j] = cw2 / lr2[j]; }

  // ---- per-wave transposed epilogue ([16][68] f32, wave-private region)
  float* Ws = (float*)(smem + w * 4352);
  const int q = l & 15, ds = l >> 4;
  #pragma unroll
  for (int ch = 0; ch < 4; ch++) {
    #pragma unroll
    for (int dtp = 0; dtp < 4; dtp++) {
      const int dt = ch * 4 + dtp;
      #pragma unroll
      for (int j = 0; j < 4; j++)
        Ws[(g * 4 + j) * 68 + dtp * 16 + c] = a1[dt][j] * r1[j] + a2[dt][j] * r2[j];
    }
    #pragma unroll
    for (int i = 0; i < 16; i++) {
      int d = ch * 64 + i * 4 + ds;
      size_t gi = bo + (size_t)d * NTOK + q0 + q;
      out[gi] = qry[gi] + Ws[q * 68 + i * 4 + ds];
    }
  }
}

extern "C" void kernel_launch(void* const* d_in, const int* in_sizes, int n_in,
                              void* d_out, int out_size, void* d_ws, size_t ws_size,
                              hipStream_t stream) {
  const float* qry  = (const float*)d_in[0];
  const float* mask = (const float*)d_in[1];
  const float* fts  = (const float*)d_in[2];
  const float* Wq   = (const float*)d_in[3];
  const float* Wk   = (const float*)d_in[4];
  const float* Wv   = (const float*)d_in[5];
  const float* mu   = (const float*)d_in[6];
  float* out = (float*)d_out;

  const size_t SZ = (size_t)BB * CC * NTOK;
  unsigned short* Qw  = (unsigned short*)d_ws;
  unsigned short* K1w = Qw + SZ;
  unsigned short* K2w = Qw + 2 * SZ;
  unsigned short* Vtw = Qw + 3 * SZ;

  dim3 pg(NTOK / 64, CC / 64, BB);
  proj_kernel<0><<<pg, 256, 0, stream>>>(qry,  Wq, Qw);    // Q  fp16, *log2e
  proj_kernel<1><<<pg, 256, 0, stream>>>(fts,  Wk, K1w);   // K1 fp16
  proj_kernel<1><<<pg, 256, 0, stream>>>(mask, Wk, K2w);   // K2 fp16
  proj_kernel<2><<<pg, 256, 0, stream>>>(fts,  Wv, Vtw);   // V^T bf16

  attn_kernel<<<BB * (NTOK / 64), 256, 0, stream>>>(Qw, K1w, K2w, Vtw, qry, mu, out);
}

// Round 8
// 256.876 us; speedup vs baseline: 4.2059x; 1.4278x over previous
//
#include <hip/hip_runtime.h>
#include <math.h>

#define BB 8
#define CC 256
#define NTOK 2304   // 48*48
#define NP 72       // 32-token pairs in attention
#define LOG2E 1.4426950408889634f
#define BIAS2 72.134752f   // p = 2^(s-BIAS2): overflow-free no-max softmax

typedef __attribute__((ext_vector_type(4))) float f32x4;
typedef __attribute__((ext_vector_type(8))) short s16x8;
typedef __attribute__((ext_vector_type(4))) short s16x4;

__device__ inline unsigned short f2bf(float x) {
  unsigned u = __builtin_bit_cast(unsigned, x);
  return (unsigned short)((u + 0x7FFFu + ((u >> 16) & 1u)) >> 16);
}
__device__ inline unsigned short f2h(float x) {
  _Float16 h = (_Float16)x;
  return __builtin_bit_cast(unsigned short, h);
}

// async global -> LDS, 16B/lane; LDS dst = wave-uniform base + lane*16
__device__ inline void async16(void* lds, const void* g) {
  __builtin_amdgcn_global_load_lds(
      (const __attribute__((address_space(1))) unsigned int*)g,
      (__attribute__((address_space(3))) unsigned int*)lds, 16, 0, 0);
}

// ---------------- prepass: X[c][n] fp32 -> Xt[n][c] fp16 (per batch) ----------------
__global__ __launch_bounds__(256)
void prep_kernel(const float* __restrict__ X, unsigned short* __restrict__ Xt) {
  __shared__ float Ls[64][65];
  const int t = threadIdx.x;
  const int n0 = blockIdx.x * 64, c0 = blockIdx.y * 64, b = blockIdx.z;
  const float* Xb = X + (size_t)b * CC * NTOK;
  unsigned short* Yb = Xt + (size_t)b * CC * NTOK;

  #pragma unroll
  for (int rr = 0; rr < 16; rr++) {
    int cl = rr * 4 + (t >> 6);
    Ls[cl][t & 63] = Xb[(size_t)(c0 + cl) * NTOK + n0 + (t & 63)];
  }
  __syncthreads();
  #pragma unroll
  for (int rr = 0; rr < 8; rr++) {
    int nl = rr * 8 + (t >> 5);
    int cl = (t & 31) * 2;
    unsigned v = (unsigned)f2h(Ls[cl][nl]) | ((unsigned)f2h(Ls[cl + 1][nl]) << 16);
    *(unsigned*)((char*)Yb + ((size_t)(n0 + nl) * CC + c0 + cl) * 2) = v;
  }
}

// ---------------- W fp32 -> fp16 ----------------
__global__ __launch_bounds__(256)
void wconv_kernel(const float* __restrict__ Wq, const float* __restrict__ Wk,
                  const float* __restrict__ Wv, unsigned short* __restrict__ Wqh,
                  unsigned short* __restrict__ Wkh, unsigned short* __restrict__ Wvh) {
  const float* src = (blockIdx.y == 0) ? Wq : (blockIdx.y == 1) ? Wk : Wv;
  unsigned short* dst = (blockIdx.y == 0) ? Wqh : (blockIdx.y == 1) ? Wkh : Wvh;
  int gi = (blockIdx.x * 256 + threadIdx.x) * 4;
  f32x4 v = *(const f32x4*)(src + gi);
  s16x4 o;
  #pragma unroll
  for (int i = 0; i < 4; i++) o[i] = (short)f2h(v[i]);
  *(s16x4*)(dst + gi) = o;
}

// ---------------- MFMA projection GEMM ----------------
// out[n][d] = sum_c Xt[n][c] * Wh[d][c]  (f16 MFMA, fp32 acc)
// MODE 0: fp16 [n][d] scaled LOG2E (Q); MODE 1: fp16 [n][d]; MODE 2: bf16 Vt [d][n]
template<int MODE>
__global__ __launch_bounds__(256, 2)
void gemm_kernel(const unsigned short* __restrict__ Xt, const unsigned short* __restrict__ Wh,
                 unsigned short* __restrict__ Y) {
  __shared__ alignas(16) char smem[32768];   // wb0|wb1 16KB each; epilogue reuse

  const int t = threadIdx.x;
  const int w = t >> 6, l = t & 63, g = l >> 4, c = l & 15;
  const int bid = blockIdx.x;
  const int b = bid & 7, nt = bid >> 3;      // batch -> XCD pin; n-tile 0..35
  const int n0w = nt * 64 + w * 16;
  const size_t bo = (size_t)b * CC * NTOK;

  const char* Xb = (const char*)(Xt + bo);
  const char* Wb = (const char*)Wh;
  char* Yb = (char*)(Y + (MODE == 2 ? bo : bo));

  // staging: 16KB tile = 32 W-rows x 512B; wave w stages chunks w+4j (j=0..3)
  int koff[4], cdst[4];
  #pragma unroll
  for (int j = 0; j < 4; j++) {
    int ck = w + 4 * j;
    int row = ck * 2 + (l >> 5);
    koff[j] = row * 512 + (((l & 31) * 16) ^ ((row & 7) << 4));
    cdst[j] = ck * 1024 + l * 16;
  }
  int kxor[8];
  #pragma unroll
  for (int dc = 0; dc < 8; dc++)
    kxor[dc] = (dc * 64 + g * 16) ^ ((c & 7) << 4);

  // A-frags: Xt rows, exactly the attn Q-load pattern
  s16x8 xa[8];
  #pragma unroll
  for (int dc = 0; dc < 8; dc++)
    xa[dc] = *(const s16x8*)(Xb + (n0w + c) * 512 + dc * 64 + g * 16);

  f32x4 acc[16];

#define STAGE_W(WB, TILE)                                            \
  do {                                                               \
    _Pragma("unroll")                                                \
    for (int j_ = 0; j_ < 4; j_++)                                   \
      async16((WB) + cdst[j_], Wb + (TILE) * 16384 + koff[j_]);      \
  } while (0)

  STAGE_W(smem, 0);
  __syncthreads();

  #pragma unroll
  for (int ph = 0; ph < 8; ph++) {
    char* cur = smem + (ph & 1) * 16384;
    if (ph < 7) STAGE_W(smem + ((ph & 1) ^ 1) * 16384, ph + 1);
    __builtin_amdgcn_s_setprio(1);
    #pragma unroll
    for (int s = 0; s < 2; s++) {
      const char* Kt = cur + (s * 16 + c) * 512;
      f32x4 sa = (f32x4){0.f, 0.f, 0.f, 0.f};
      #pragma unroll
      for (int dc = 0; dc < 8; dc++) {
        s16x8 wf = *(const s16x8*)(Kt + kxor[dc]);
        sa = __builtin_amdgcn_mfma_f32_16x16x32_f16(xa[dc], wf, sa, 0, 0, 0);
      }
      acc[ph * 2 + s] = sa;
    }
    __builtin_amdgcn_s_setprio(0);
    __syncthreads();
  }
#undef STAGE_W

  if (MODE == 0 || MODE == 1) {
    // stage wave's 16n x 256d fp16 tile, write [n][d] rows coalesced
    unsigned short* Ws = (unsigned short*)(smem + w * 8192);   // [16][256]
    #pragma unroll
    for (int dt = 0; dt < 16; dt++)
      #pragma unroll
      for (int j = 0; j < 4; j++) {
        float v = (MODE == 0) ? acc[dt][j] * LOG2E : acc[dt][j];
        Ws[(g * 4 + j) * 256 + dt * 16 + c] = f2h(v);
      }
    // wave-local write->read (compiler inserts lgkmcnt)
    #pragma unroll
    for (int r = 0; r < 16; r++) {
      s16x4 v = *(const s16x4*)&Ws[r * 256 + l * 4];
      *(s16x4*)(Yb + (size_t)(n0w + r) * 512 + l * 8) = v;
    }
  } else {
    // Vt bf16 [d][n]: per d-tile, 16x16 LDS transpose then 32B-row stores
    unsigned short* Vs = (unsigned short*)(smem + w * 8192);   // [16][20]
    #pragma unroll
    for (int dt = 0; dt < 16; dt++) {
      s16x4 pv;
      #pragma unroll
      for (int j = 0; j < 4; j++) pv[j] = (short)f2bf(acc[dt][j]);
      *(s16x4*)&Vs[c * 20 + g * 4] = pv;
      s16x4 vv = *(const s16x4*)&Vs[(l >> 2) * 20 + (l & 3) * 4];
      *(s16x4*)(Yb + (size_t)(dt * 16 + (l >> 2)) * 4608 + (size_t)(n0w + (l & 3) * 4) * 2) = vv;
    }
  }
}

// ---------------- fused dual-softmax MFMA attention (R7 structure + setprio) ----------------
__global__ __launch_bounds__(256, 2)
void attn_kernel(const unsigned short* __restrict__ Qf, const unsigned short* __restrict__ K1,
                 const unsigned short* __restrict__ K2, const unsigned short* __restrict__ Vt,
                 const float* __restrict__ qry, const float* __restrict__ mup,
                 float* __restrict__ out) {
  __shared__ alignas(16) char smem[79360];
  char* const kb0 = smem;
  char* const kb1 = smem + 16384;

  const int t = threadIdx.x;
  const int w = t >> 6, l = t & 63, g = l >> 4, c = l & 15;
  const int bid = blockIdx.x;
  const int b = bid & 7, qt = bid >> 3;     // batch -> XCD pin
  const int q0 = qt * 64 + w * 16;
  const size_t bo = (size_t)b * CC * NTOK;

  const char* Qb  = (const char*)(Qf + bo);
  const char* K1b = (const char*)(K1 + bo);
  const char* K2b = (const char*)(K2 + bo);
  const char* Vtb = (const char*)(Vt + bo);

  float* const Pe0 = (float*)(smem + 65536 + w * 3456);
  float* const Pe1 = Pe0 + 288;
  float* const Pod = Pe0 + 576;

  int koff[2], voff[2], cdst[2];
  #pragma unroll
  for (int j = 0; j < 2; j++) {
    int ck = w + 4 * j;
    int tok = ck * 2 + (l >> 5);
    koff[j] = tok * 512 + (((l & 31) * 16) ^ ((tok & 7) << 4));
    voff[j] = (ck * 32 + (l >> 1)) * 4608 + (l & 1) * 16;
    cdst[j] = ck * 1024 + l * 16;
  }

  int kxor[8];
  #pragma unroll
  for (int dc = 0; dc < 8; dc++)
    kxor[dc] = (dc * 64 + g * 16) ^ ((c & 7) << 4);

  s16x8 qf[8];
  #pragma unroll
  for (int dc = 0; dc < 8; dc++)
    qf[dc] = *(const s16x8*)(Qb + (q0 + c) * 512 + dc * 64 + g * 16);

  f32x4 a1[16], a2[16];
  #pragma unroll
  for (int dt = 0; dt < 16; dt++) {
    a1[dt] = (f32x4){0.f, 0.f, 0.f, 0.f};
    a2[dt] = (f32x4){0.f, 0.f, 0.f, 0.f};
  }
  float lr1[4] = {0.f, 0.f, 0.f, 0.f};
  float lr2[4] = {0.f, 0.f, 0.f, 0.f};

#define STAGE_K(KB, TILE)                                                  \
  do {                                                                     \
    _Pragma("unroll")                                                      \
    for (int pp_ = 0; pp_ < 2; pp_++) {                                    \
      const char* ks_ = (pp_ ? K2b : K1b) + (size_t)(TILE) * 8192;         \
      async16((KB) + pp_ * 8192 + cdst[0], ks_ + koff[0]);                 \
      async16((KB) + pp_ * 8192 + cdst[1], ks_ + koff[1]);                 \
    }                                                                      \
  } while (0)

#define STAGE_V(VB, PAIR)                                                  \
  do {                                                                     \
    _Pragma("unroll")                                                      \
    for (int h_ = 0; h_ < 2; h_++) {                                       \
      const char* vs_ = Vtb + (PAIR) * 64 + h_ * 32;                       \
      async16((VB) + h_ * 8192 + cdst[0], vs_ + voff[0]);                  \
      async16((VB) + h_ * 8192 + cdst[1], vs_ + voff[1]);                  \
    }                                                                      \
  } while (0)

  STAGE_K(kb0, 0);
  STAGE_V(smem + 32768, 0);
  __syncthreads();

  for (int p = 0; p < NP; p++) {
    char* vcur = smem + 32768 + (p & 1) * 16384;
    char* vnxt = smem + 32768 + ((p & 1) ^ 1) * 16384;

    // even phase: tile 2p from kb0
    STAGE_K(kb1, 2 * p + 1);
    #pragma unroll
    for (int pp = 0; pp < 2; pp++) {
      const char* Kt = kb0 + pp * 8192 + c * 512;
      f32x4 s = (f32x4){0.f, 0.f, 0.f, 0.f};
      __builtin_amdgcn_s_setprio(1);
      #pragma unroll
      for (int dc = 0; dc < 8; dc++) {
        s16x8 kf = *(const s16x8*)(Kt + kxor[dc]);
        s = __builtin_amdgcn_mfma_f32_16x16x32_f16(qf[dc], kf, s, 0, 0, 0);
      }
      __builtin_amdgcn_s_setprio(0);
      float* lr = pp ? lr2 : lr1;
      float* Pe = pp ? Pe1 : Pe0;
      #pragma unroll
      for (int j = 0; j < 4; j++) {
        float pv = exp2f(s[j] - BIAS2);
        lr[j] += pv;
        Pe[(g * 4 + j) * 18 + c] = pv;
      }
    }
    __syncthreads();

    // odd phase: tile 2p+1 from kb1, PV on vcur
    if (p + 1 < NP) {
      STAGE_K(kb0, 2 * p + 2);
      STAGE_V(vnxt, p + 1);
    }
    s16x8 pa0, pa1;
    #pragma unroll
    for (int pp = 0; pp < 2; pp++) {
      const char* Kt = kb1 + pp * 8192 + c * 512;
      f32x4 s = (f32x4){0.f, 0.f, 0.f, 0.f};
      __builtin_amdgcn_s_setprio(1);
      #pragma unroll
      for (int dc = 0; dc < 8; dc++) {
        s16x8 kf = *(const s16x8*)(Kt + kxor[dc]);
        s = __builtin_amdgcn_mfma_f32_16x16x32_f16(qf[dc], kf, s, 0, 0, 0);
      }
      __builtin_amdgcn_s_setprio(0);
      float* lr = pp ? lr2 : lr1;
      #pragma unroll
      for (int j = 0; j < 4; j++) {
        float pv = exp2f(s[j] - BIAS2);
        lr[j] += pv;
        Pod[(g * 4 + j) * 18 + c] = pv;
      }
      const float* src = ((g < 2) ? (pp ? Pe1 : Pe0) : Pod) + c * 18 + (g & 1) * 8;
      s16x8 v;
      #pragma unroll
      for (int i = 0; i < 8; i++) v[i] = (short)f2bf(src[i]);
      if (pp == 0) pa0 = v; else pa1 = v;
    }
    {
      const char* vbase = vcur + ((g >= 2) ? 8192 : 0) + c * 32 + (g & 1) * 16;
      __builtin_amdgcn_s_setprio(1);
      #pragma unroll
      for (int dt = 0; dt < 16; dt++) {
        s16x8 vf = *(const s16x8*)(vbase + dt * 512);
        a1[dt] = __builtin_amdgcn_mfma_f32_16x16x32_bf16(pa0, vf, a1[dt], 0, 0, 0);
        a2[dt] = __builtin_amdgcn_mfma_f32_16x16x32_bf16(pa1, vf, a2[dt], 0, 0, 0);
      }
      __builtin_amdgcn_s_setprio(0);
    }
    __syncthreads();
  }
#undef STAGE_K
#undef STAGE_V

  #pragma unroll
  for (int j = 0; j < 4; j++) {
    #pragma unroll
    for (int off = 1; off < 16; off <<= 1) {
      lr1[j] += __shfl_xor(lr1[j], off);
      lr2[j] += __shfl_xor(lr2[j], off);
    }
  }
  const float mu = mup[0];
  const float cw1 = 0.5f / (0.5f + mu);
  const float cw2 = mu / (0.5f + mu);
  float r1[4], r2[4];
  #pragma unroll
  for (int j = 0; j < 4; j++) { r1[j] = cw1 / lr1[j]; r2[j] = cw2 / lr2[j]; }

  float* Ws = (float*)(smem + w * 4352);
  const int q = l & 15, ds = l >> 4;
  #pragma unroll
  for (int ch = 0; ch < 4; ch++) {
    #pragma unroll
    for (int dtp = 0; dtp < 4; dtp++) {
      const int dt = ch * 4 + dtp;
      #pragma unroll
      for (int j = 0; j < 4; j++)
        Ws[(g * 4 + j) * 68 + dtp * 16 + c] = a1[dt][j] * r1[j] + a2[dt][j] * r2[j];
    }
    #pragma unroll
    for (int i = 0; i < 16; i++) {
      int d = ch * 64 + i * 4 + ds;
      size_t gi = bo + (size_t)d * NTOK + q0 + q;
      out[gi] = qry[gi] + Ws[q * 68 + i * 4 + ds];
    }
  }
}

extern "C" void kernel_launch(void* const* d_in, const int* in_sizes, int n_in,
                              void* d_out, int out_size, void* d_ws, size_t ws_size,
                              hipStream_t stream) {
  const float* qry  = (const float*)d_in[0];
  const float* mask = (const float*)d_in[1];
  const float* fts  = (const float*)d_in[2];
  const float* Wq   = (const float*)d_in[3];
  const float* Wk   = (const float*)d_in[4];
  const float* Wv   = (const float*)d_in[5];
  const float* mu   = (const float*)d_in[6];
  float* out = (float*)d_out;

  const size_t SZ = (size_t)BB * CC * NTOK;
  unsigned short* Xtq = (unsigned short*)d_ws;
  unsigned short* Xtm = Xtq + SZ;
  unsigned short* Xtf = Xtq + 2 * SZ;
  unsigned short* Qw  = Xtq + 3 * SZ;
  unsigned short* K1w = Xtq + 4 * SZ;
  unsigned short* K2w = Xtq + 5 * SZ;
  unsigned short* Vtw = Xtq + 6 * SZ;
  unsigned short* Wqh = Xtq + 7 * SZ;
  unsigned short* Wkh = Wqh + CC * CC;
  unsigned short* Wvh = Wkh + CC * CC;

  dim3 pg(NTOK / 64, CC / 64, BB);           // 36 x 4 x 8
  prep_kernel<<<pg, 256, 0, stream>>>(qry,  Xtq);
  prep_kernel<<<pg, 256, 0, stream>>>(mask, Xtm);
  prep_kernel<<<pg, 256, 0, stream>>>(fts,  Xtf);
  wconv_kernel<<<dim3(64, 3), 256, 0, stream>>>(Wq, Wk, Wv, Wqh, Wkh, Wvh);

  const int GG = BB * (NTOK / 64);           // 288
  gemm_kernel<0><<<GG, 256, 0, stream>>>(Xtq, Wqh, Qw);
  gemm_kernel<1><<<GG, 256, 0, stream>>>(Xtf, Wkh, K1w);
  gemm_kernel<1><<<GG, 256, 0, stream>>>(Xtm, Wkh, K2w);
  gemm_kernel<2><<<GG, 256, 0, stream>>>(Xtf, Wvh, Vtw);

  attn_kernel<<<GG, 256, 0, stream>>>(Qw, K1w, K2w, Vtw, qry, mu, out);
}